// Round 16
// baseline (106.762 us; speedup 1.0000x reference)
//
#include <hip/hip_runtime.h>

#define LSEQ 512
#define NB 64
#define NCHUNK 41  // 16*41 = 656 >= 512 + 1*80 + 63 = 655 steps

// lanes 1..63 <- x[lane-1]; lane 0 <- old[0] (wave_shr:1, bound_ctrl=0).
__device__ __forceinline__ float dpp_shr1(float old, float x) {
  return __int_as_float(__builtin_amdgcn_update_dpp(
      __float_as_int(old), __float_as_int(x), 0x138, 0xF, 0xF, false));
}
// lane l <- lane l+1 (wave_shl:1) — rotates injection registers.
__device__ __forceinline__ float dpp_shl1(float x) {
  return __int_as_float(__builtin_amdgcn_update_dpp(
      0, __float_as_int(x), 0x130, 0xF, 0xF, false));
}

// (d,e) pair encodes v = d - log2(e); exact softmin, log deferred to the end.
__device__ __forceinline__ void renorm(float& d, float& e) {
  const int eb = __float_as_int(e);
  const int E = (eb >> 23) - 127;
  e = __int_as_float((eb & 0x007FFFFF) | 0x3F800000);
  d -= (float)E;
}

// One softmin cell on (d,e) pairs: preds diag (ad,ae), up (bd,be), left
// (cd,ce). M = min3 of d's; e_new = sum exp2(M-d_i)*e_i; d_new = diff^2 + M.
__device__ __forceinline__ void cell(float p, float t, float ad, float ae,
                                     float bd, float be, float cd, float ce,
                                     float& od, float& oe) {
  const float diff = p - t;
  const float M = fminf(fminf(ad, bd), cd);
  oe = (__builtin_amdgcn_exp2f(M - ad) * ae +
        __builtin_amdgcn_exp2f(M - bd) * be) +
       __builtin_amdgcn_exp2f(M - cd) * ce;
  od = __builtin_fmaf(diff, diff, M);
}

// One 16-step chunk, FOUR rows per lane (i0..i3 = 256w+4l+1..4), all at
// column j = cbase+1+u-lane. Cell0's up/diag come from lane l-1 (DPP / lane-0
// ring injection); cells 1..3 chain lane-locally (diag = v_{k-1} old, up =
// fresh d_{k-1}) -> movement ops amortized 4x vs R13.
template <bool FULL>
__device__ __forceinline__ void chunk16(
    int cbase, const float* tg, const float2* ring2P, float2* ring2W,
    float p0, float p1, float p2, float p3, bool is_wr, int lane, float& v0d,
    float& v0e, float& v1d, float& v1e, float& v2d, float& v2e, float& v3d,
    float& v3e, float& r0d, float& r0e, float& tcur) {
  renorm(v0d, v0e);
  renorm(v1d, v1e);
  renorm(v2d, v2e);
  renorm(v3d, v3e);

  // injection registers: lane k (mod 16) holds step-k data for lane 0
  float tinj = tg[(cbase + (lane & 15)) & 511];
  const float2 rj = ring2P[(cbase + 1 + (lane & 15)) & 127];
  float rdinj = rj.x, reinj = rj.y;

  float vvd[16], vve[16];
#pragma unroll
  for (int u = 0; u < 16; ++u) {
    tcur = dpp_shr1(tinj, tcur);             // target'[j-1] (shared by rows)
    const float r1d = dpp_shr1(rdinj, v3d);  // R'[i0-1][j] pair from lane l-1
    const float r1e = dpp_shr1(reinj, v3e);
    if (u < 15) {  // rotate injections for next step
      tinj = dpp_shl1(tinj);
      rdinj = dpp_shl1(rdinj);
      reinj = dpp_shl1(reinj);
    }
    float d0, e0, d1, e1, d2, e2, d3, e3;
    cell(p0, tcur, r0d, r0e, r1d, r1e, v0d, v0e, d0, e0);
    cell(p1, tcur, v0d, v0e, d0, e0, v1d, v1e, d1, e1);
    cell(p2, tcur, v1d, v1e, d1, e1, v2d, v2e, d2, e2);
    cell(p3, tcur, v2d, v2e, d2, e2, v3d, v3e, d3, e3);
    vvd[u] = d3;
    vve[u] = e3;
    if (FULL) {
      v0d = d0; v0e = e0; v1d = d1; v1e = e1;
      v2d = d2; v2e = e2; v3d = d3; v3e = e3;
    } else {
      const int j = cbase + 1 + u - lane;  // same column for all 4 rows
      const bool act = ((unsigned)(j - 1)) < (unsigned)LSEQ;
      v0d = act ? d0 : v0d; v0e = act ? e0 : v0e;
      v1d = act ? d1 : v1d; v1e = act ? e1 : v1e;
      v2d = act ? d2 : v2d; v2e = act ? e2 : v2e;
      v3d = act ? d3 : v3d; v3e = act ? e3 : v3e;
    }
    r0d = r1d;
    r0e = r1e;
  }

  if (is_wr) {  // lane 63 of wave 0 publishes row 256 (its i3)
    const int j0 = cbase - 62;
#pragma unroll
    for (int k = 0; k < 16; ++k) {
      if (FULL || (((unsigned)(j0 + k - 1)) < (unsigned)LSEQ))
        ring2W[(j0 + k) & 127] = make_float2(vvd[k], vve[k]);
    }
  }
}

// Soft-DTW banded wavefront, one block per batch, 2 waves x 64 lanes x 4 rows.
// Lane l of wave w owns rows 256w+4l+1..+4; column j = s - 80w - l at step s.
// Ring (lag=80, Delta=16): reader (wave 1) at top of chunk c reads cols
// [16c-79, 16c-64], written by wave 0 at steps <= 16c-1 (chunk c-1), burst
// before the top-of-c barrier. During chunk c's body wave 0 writes cols
// [16c-62, 16c-47] — disjoint from the read window; mod-128 distance 32.
__global__ __launch_bounds__(128) void dtw_band(
    const float* __restrict__ pred, const float* __restrict__ target,
    float* __restrict__ part) {
  const int b = blockIdx.x;
  const int tid = threadIdx.x;  // 0..127
  const int w = tid >> 6;
  const int lane = tid & 63;
  const bool is_wr = (lane == 63) && (w == 0);

  __shared__ float tg[LSEQ];
  __shared__ float2 rings2[2][128];  // row 0: interface; row 1: INF dummy

  const float SC = 3.79828146f;  // sqrt(C1), C1 = (1/g)*log2(e), g = 0.1
  const float4 pp = ((const float4*)(pred + b * LSEQ))[tid];
  const float p0 = pp.x * SC, p1 = pp.y * SC, p2 = pp.z * SC, p3 = pp.w * SC;
  const float4 tt = ((const float4*)(target + b * LSEQ))[tid];
  ((float4*)tg)[tid] = make_float4(tt.x * SC, tt.y * SC, tt.z * SC, tt.w * SC);
  ((float2*)rings2)[tid] = make_float2(INFINITY, 1.0f);
  ((float2*)rings2)[tid + 128] = make_float2(INFINITY, 1.0f);

  const int cw0 = 5 * w;  // wave-active chunks: [cw0, cw0+35]; lag = 80w
  const float2* __restrict__ ring2P = rings2[w == 0 ? 1 : 0];
  float2* __restrict__ ring2W = rings2[0];

  float v0d = INFINITY, v0e = 1.0f;          // R'[i0][j-1]
  float v1d = INFINITY, v1e = 1.0f;
  float v2d = INFINITY, v2e = 1.0f;
  float v3d = INFINITY, v3e = 1.0f;
  float r0d = (tid == 0) ? 0.0f : INFINITY;  // R'[i0-1][j-1]; seed R'[0][0]
  float r0e = 1.0f;
  float tcur = 0.0f;

  for (int c = 0; c < NCHUNK; ++c) {
    __syncthreads();  // top of chunk c (also orders init writes at c=0)
    if (c < cw0 || c > cw0 + 35) continue;  // wave-uniform
    const int cbase = 16 * c - 80 * w;
    if (c >= cw0 + 4 && c <= cw0 + 31)
      chunk16<true>(cbase, tg, ring2P, ring2W, p0, p1, p2, p3, is_wr, lane,
                    v0d, v0e, v1d, v1e, v2d, v2e, v3d, v3e, r0d, r0e, tcur);
    else
      chunk16<false>(cbase, tg, ring2P, ring2W, p0, p1, p2, p3, is_wr, lane,
                     v0d, v0e, v1d, v1e, v2d, v2e, v3d, v3e, r0d, r0e, tcur);
  }

  if (tid == 127)  // row 512 = wave 1, lane 63, i3; unscale by 1/C1 = g*ln2
    part[b] = (v3d - __builtin_amdgcn_logf(v3e)) * 0.069314718f;
}

__global__ void dtw_reduce(const float* __restrict__ part,
                           float* __restrict__ out) {
  float v = part[threadIdx.x];
#pragma unroll
  for (int o = 32; o > 0; o >>= 1) v += __shfl_down(v, o);
  if (threadIdx.x == 0) out[0] = v * (1.0f / NB);
}

extern "C" void kernel_launch(void* const* d_in, const int* in_sizes, int n_in,
                              void* d_out, int out_size, void* d_ws,
                              size_t ws_size, hipStream_t stream) {
  const float* pred = (const float*)d_in[0];
  const float* target = (const float*)d_in[1];
  float* part = (float*)d_ws;

  dtw_band<<<NB, 128, 0, stream>>>(pred, target, part);
  dtw_reduce<<<1, 64, 0, stream>>>(part, (float*)d_out);
}

// Round 17
// 90.476 us; speedup vs baseline: 1.1800x; 1.1800x over previous
//
#include <hip/hip_runtime.h>

#define LSEQ 512
#define NB 64
#define NCHUNK 51  // 16*51 = 816 >= 512 + 3*80 + 63 = 815 steps

// lanes 1..63 <- x[lane-1]; lane 0 <- old[0] (wave_shr:1, bound_ctrl=0).
__device__ __forceinline__ float dpp_shr1(float old, float x) {
  return __int_as_float(__builtin_amdgcn_update_dpp(
      __float_as_int(old), __float_as_int(x), 0x138, 0xF, 0xF, false));
}
// lane l <- lane l+1 (wave_shl:1) — rotates injection registers.
__device__ __forceinline__ float dpp_shl1(float x) {
  return __int_as_float(__builtin_amdgcn_update_dpp(
      0, __float_as_int(x), 0x130, 0xF, 0xF, false));
}

// (d,e) pair encodes v = d - log2(e); exact softmin, log deferred to the end.
__device__ __forceinline__ void renorm(float& d, float& e) {
  const int eb = __float_as_int(e);
  const int E = (eb >> 23) - 127;
  e = __int_as_float((eb & 0x007FFFFF) | 0x3F800000);
  d -= (float)E;
}

// One 16-step chunk, 2 rows/lane. IDENTICAL schedule/arithmetic to R13; the
// only change: the 6 exp2 are issued as a contiguous asm-volatile batch with
// 6 forced distinct result regs. Diagnosis: all passing variants sat at
// VGPR=36 — allocator reused 2-3 regs for exp2 results, serializing
// exp2->use->exp2->use, ~6x25cy of exposed trans latency = the ~150cy/step
// gap between issue (~100cy) and wall (253cy). Batch -> latencies overlap.
template <bool FULL>
__device__ __forceinline__ void chunk16(
    int cbase, const float* tg, const float2* ring2P, float2* ring2W, float p0,
    float p1, bool is_wr, int lane, float& v0d, float& v0e, float& v1d,
    float& v1e, float& r0d, float& r0e, float& tcur) {
  renorm(v0d, v0e);
  renorm(v1d, v1e);

  // injection registers: lane k (mod 16) holds step-k data for lane 0
  float tinj = tg[(cbase + (lane & 15)) & 511];
  const float2 rj = ring2P[(cbase + 1 + (lane & 15)) & 127];
  float rdinj = rj.x, reinj = rj.y;

  float vvd[16], vve[16];
#pragma unroll
  for (int u = 0; u < 16; ++u) {
    tcur = dpp_shr1(tinj, tcur);             // target'[j-1] (shared by rows)
    const float r1d = dpp_shr1(rdinj, v1d);  // R'[i0-1][j] pair
    const float r1e = dpp_shr1(reinj, v1e);
    if (u < 15) {  // rotate injections for next step
      tinj = dpp_shl1(tinj);
      rdinj = dpp_shl1(rdinj);
      reinj = dpp_shl1(reinj);
    }
    // ---- d-chains (fast VALU path) ----
    const float diff0 = p0 - tcur;
    const float M0 = fminf(fminf(r0d, r1d), v0d);
    const float d0 = __builtin_fmaf(diff0, diff0, M0);
    const float diff1 = p1 - tcur;
    const float M1 = fminf(fminf(v0d, d0), v1d);
    const float d1 = __builtin_fmaf(diff1, diff1, M1);
    // ---- exp2 batch: args first, then 6 back-to-back trans ops ----
    const float a0 = M0 - r0d, a1 = M0 - r1d, a2 = M0 - v0d;
    const float b0 = M1 - v0d, b1 = M1 - d0, b2 = M1 - v1d;
    float x0, x1, x2, x3, x4, x5;
    asm volatile("v_exp_f32 %0, %1" : "=v"(x0) : "v"(a0));
    asm volatile("v_exp_f32 %0, %1" : "=v"(x1) : "v"(a1));
    asm volatile("v_exp_f32 %0, %1" : "=v"(x2) : "v"(a2));
    asm volatile("v_exp_f32 %0, %1" : "=v"(x3) : "v"(b0));
    asm volatile("v_exp_f32 %0, %1" : "=v"(x4) : "v"(b1));
    asm volatile("v_exp_f32 %0, %1" : "=v"(x5) : "v"(b2));
    // ---- e combines ----
    const float e0 = __builtin_fmaf(
        x2, v0e, __builtin_fmaf(x1, r1e, x0 * r0e));
    const float e1 = __builtin_fmaf(
        x5, v1e, __builtin_fmaf(x4, e0, x3 * v0e));
    vvd[u] = d1;
    vve[u] = e1;
    if (FULL) {
      v0d = d0; v0e = e0; v1d = d1; v1e = e1;
    } else {
      const int j = cbase + 1 + u - lane;
      const bool act = ((unsigned)(j - 1)) < (unsigned)LSEQ;
      v0d = act ? d0 : v0d; v0e = act ? e0 : v0e;  // inactive lanes keep
      v1d = act ? d1 : v1d; v1e = act ? e1 : v1e;  // (INF,1); NaN discarded
    }
    r0d = r1d;
    r0e = r1e;
  }

  if (is_wr) {  // lane 63 publishes row 128(w+1) = its i1
    const int j0 = cbase - 62;
#pragma unroll
    for (int k = 0; k < 16; ++k) {
      if (FULL || (((unsigned)(j0 + k - 1)) < (unsigned)LSEQ))
        ring2W[(j0 + k) & 127] = make_float2(vvd[k], vve[k]);
    }
  }
}

// Soft-DTW banded wavefront, one block per batch, 4 waves x 64 lanes x 2 rows.
// Lane l of wave w owns rows 128w+2l+1, +2; column j = s - 80w - l at step s.
// Ring (lag=80): entry col J read by wave w at top of chunk c was written by
// wave w-1 in its chunk c-1, burst before the top-of-c barrier; concurrent
// writes land +18..+33 past the read window (disjoint mod 128).
__global__ __launch_bounds__(256) void dtw_band(
    const float* __restrict__ pred, const float* __restrict__ target,
    float* __restrict__ part) {
  const int b = blockIdx.x;
  const int tid = threadIdx.x;  // 0..255
  const int w = tid >> 6;
  const int lane = tid & 63;
  const bool is_wr = (lane == 63) && (w < 3);

  __shared__ float tg[LSEQ];
  __shared__ float2 rings2[4][128];  // rows 0..2: interfaces; row 3: INF dummy

  const float SC = 3.79828146f;  // sqrt(C1), C1 = (1/g)*log2(e), g = 0.1
  const float2 pp = ((const float2*)(pred + b * LSEQ))[tid];
  const float p0 = pp.x * SC, p1 = pp.y * SC;  // rows 2*tid+1, 2*tid+2
  const float2 tt = ((const float2*)(target + b * LSEQ))[tid];
  ((float2*)tg)[tid] = make_float2(tt.x * SC, tt.y * SC);
  ((float2*)rings2)[tid] = make_float2(INFINITY, 1.0f);
  ((float2*)rings2)[tid + 256] = make_float2(INFINITY, 1.0f);

  const int lag = w * 80;
  const int cw0 = 5 * w;  // wave-active chunks: [cw0, cw0+35]
  const float2* __restrict__ ring2P = rings2[w == 0 ? 3 : w - 1];
  float2* __restrict__ ring2W = rings2[w];

  float v0d = INFINITY, v0e = 1.0f;          // R'[i0][j-1]
  float v1d = INFINITY, v1e = 1.0f;          // R'[i1][j-1]
  float r0d = (tid == 0) ? 0.0f : INFINITY;  // R'[i0-1][j-1]; seed R'[0][0]
  float r0e = 1.0f;
  float tcur = 0.0f;

  for (int c = 0; c < NCHUNK; ++c) {
    __syncthreads();  // top of chunk c (also orders init writes at c=0)
    if (c < cw0 || c > cw0 + 35) continue;  // wave-uniform
    const int cbase = 16 * c - lag;
    if (c >= cw0 + 4 && c <= cw0 + 31)
      chunk16<true>(cbase, tg, ring2P, ring2W, p0, p1, is_wr, lane, v0d, v0e,
                    v1d, v1e, r0d, r0e, tcur);
    else
      chunk16<false>(cbase, tg, ring2P, ring2W, p0, p1, is_wr, lane, v0d, v0e,
                     v1d, v1e, r0d, r0e, tcur);
  }

  if (tid == 255)  // row 512 = wave 3 lane 63 i1; unscale by 1/C1 = g*ln2
    part[b] = (v1d - __builtin_amdgcn_logf(v1e)) * 0.069314718f;
}

__global__ void dtw_reduce(const float* __restrict__ part,
                           float* __restrict__ out) {
  float v = part[threadIdx.x];
#pragma unroll
  for (int o = 32; o > 0; o >>= 1) v += __shfl_down(v, o);
  if (threadIdx.x == 0) out[0] = v * (1.0f / NB);
}

extern "C" void kernel_launch(void* const* d_in, const int* in_sizes, int n_in,
                              void* d_out, int out_size, void* d_ws,
                              size_t ws_size, hipStream_t stream) {
  const float* pred = (const float*)d_in[0];
  const float* target = (const float*)d_in[1];
  float* part = (float*)d_ws;

  dtw_band<<<NB, 256, 0, stream>>>(pred, target, part);
  dtw_reduce<<<1, 64, 0, stream>>>(part, (float*)d_out);
}